// Round 4
// baseline (258.613 us; speedup 1.0000x reference)
//
#include <hip/hip_runtime.h>
#include <hip/hip_fp16.h>

#define NQ 20

__device__ __forceinline__ float bcast_first(float x) {
    return __int_as_float(__builtin_amdgcn_readfirstlane(__float_as_int(x)));
}

// RX butterfly, symmetric form: new = C*mine + SV*(partner.im, -partner.re)
__device__ __forceinline__ void bfly(float C, float SV, float2& a, float2& b) {
    float2 na = make_float2(C * a.x + SV * b.y, C * a.y - SV * b.x);
    float2 nb = make_float2(C * b.x + SV * a.y, C * b.y - SV * a.x);
    a = na; b = nb;
}

// vectorized over two complex packed in float4
__device__ __forceinline__ void bfly4(float C, float SV, float4& a, float4& b) {
    float4 na = make_float4(C*a.x + SV*b.y, C*a.y - SV*b.x, C*a.z + SV*b.w, C*a.w - SV*b.z);
    float4 nb = make_float4(C*b.x + SV*a.y, C*b.y - SV*a.x, C*b.z + SV*a.w, C*b.w - SV*a.z);
    a = na; b = nb;
}

// fp16 pack/unpack: 2 complex <-> 8 bytes
__device__ __forceinline__ float4 h4_to_f4(float2 raw) {
    __half2* h = (__half2*)&raw;
    float2 a = __half22float2(h[0]);
    float2 b = __half22float2(h[1]);
    return make_float4(a.x, a.y, b.x, b.y);
}
__device__ __forceinline__ float2 f4_to_h4(float4 v) {
    float2 r;
    __half2* h = (__half2*)&r;
    h[0] = __float22half2_rn(make_float2(v.x, v.y));
    h[1] = __float22half2_rn(make_float2(v.z, v.w));
    return r;
}

// swizzled LDS index for pass1: XOR bits 2..4 by bits 7..9 of the local index
__device__ __forceinline__ int swz1(int l) { return l ^ (((l >> 7) & 7) << 2); }

// Pass 1: state-index bits 0..10 (qubits 19..9). One wave owns 2048 contiguous
// complex. Three register assignments, two in-wave LDS exchanges, no shuffles.
// FP16=true: final store packs pairs to __half2 intermediate (ws).
template <bool FP16>
__global__ __launch_bounds__(64) void rx_pass1(
        const float* __restrict__ phi, const float* __restrict__ thetas,
        float2* __restrict__ out, __half2* __restrict__ inter) {
    __shared__ float2 lds[2048];                    // 16 KiB
    const int lane = threadIdx.x;
    const int W = blockIdx.x;                       // [0, 8192)
    const int b = W >> 9;
    const int base = (W & 511) << 11;
    const float* ph = phi + ((size_t)b << NQ) + base;

    float c[11], sv[11];
#pragma unroll
    for (int beta = 0; beta < 11; ++beta) {
        float th = 0.5f * thetas[b * NQ + (NQ - 1 - beta)];
        c[beta]  = bcast_first(cosf(th));
        sv[beta] = bcast_first(sinf(th));
    }

    float2 v[32];
#pragma unroll
    for (int k4 = 0; k4 < 8; ++k4) {
        float4 t = *(const float4*)(ph + (k4 << 8) + (lane << 2));
        v[k4 * 4 + 0] = make_float2(t.x, 0.f);
        v[k4 * 4 + 1] = make_float2(t.y, 0.f);
        v[k4 * 4 + 2] = make_float2(t.z, 0.f);
        v[k4 * 4 + 3] = make_float2(t.w, 0.f);
    }

    const int regbit1[5]  = {0, 1, 8, 9, 10};
    const int regmask1[5] = {1, 2, 4, 8, 16};
#pragma unroll
    for (int t = 0; t < 5; ++t) {
        const float C = c[regbit1[t]], SV = sv[regbit1[t]];
        const int m = regmask1[t];
#pragma unroll
        for (int r = 0; r < 32; ++r)
            if (!(r & m)) bfly(C, SV, v[r], v[r | m]);
    }

#pragma unroll
    for (int k4 = 0; k4 < 8; ++k4) {
        int low0 = (k4 << 8) + (lane << 2);
        int s0 = swz1(low0);
        *(float4*)&lds[s0]     = make_float4(v[k4*4+0].x, v[k4*4+0].y, v[k4*4+1].x, v[k4*4+1].y);
        *(float4*)&lds[s0 + 2] = make_float4(v[k4*4+2].x, v[k4*4+2].y, v[k4*4+3].x, v[k4*4+3].y);
    }
    __syncthreads();

    {
        const int g = lane >> 2, lam = lane & 3;
        float2 w2[32];
#pragma unroll
        for (int r = 0; r < 32; ++r) {
            int l = (g << 7) | (r << 2) | lam;
            w2[r] = lds[swz1(l)];
        }
#pragma unroll
        for (int t = 0; t < 5; ++t) {
            const float C = c[2 + t], SV = sv[2 + t];
            const int m = 1 << t;
#pragma unroll
            for (int r = 0; r < 32; ++r)
                if (!(r & m)) bfly(C, SV, w2[r], w2[r | m]);
        }
#pragma unroll
        for (int r = 0; r < 32; ++r) {
            int l = (g << 7) | (r << 2) | lam;
            lds[swz1(l)] = w2[r];
        }
    }
    __syncthreads();

    float4 u[16];
#pragma unroll
    for (int m = 0; m < 16; ++m) {
        int l0 = (lane << 1) | ((m & 1) << 7) | (((m >> 1) & 1) << 8)
               | (((m >> 2) & 1) << 9) | (((m >> 3) & 1) << 10);
        u[m] = *(float4*)&lds[swz1(l0)];
    }
    {
        const float C = c[7], SV = sv[7];
#pragma unroll
        for (int m = 0; m < 16; m += 2) {
            float4 A = u[m], B = u[m + 1];
            u[m]     = make_float4(C*A.x + SV*B.y, C*A.y - SV*B.x, C*A.z + SV*B.w, C*A.w - SV*B.z);
            u[m + 1] = make_float4(C*B.x + SV*A.y, C*B.y - SV*A.x, C*B.z + SV*A.w, C*B.w - SV*A.z);
        }
    }
    if (FP16) {
        __half2* ip = inter + ((size_t)b << NQ) + base;
#pragma unroll
        for (int m = 0; m < 16; ++m) {
            int l0 = (lane << 1) | ((m & 1) << 7) | (((m >> 1) & 1) << 8)
                   | (((m >> 2) & 1) << 9) | (((m >> 3) & 1) << 10);
            *(float2*)&ip[l0] = f4_to_h4(u[m]);
        }
    } else {
        float2* op = out + ((size_t)b << NQ) + base;
#pragma unroll
        for (int m = 0; m < 16; ++m) {
            int l0 = (lane << 1) | ((m & 1) << 7) | (((m >> 1) & 1) << 8)
                   | (((m >> 2) & 1) << 9) | (((m >> 3) & 1) << 10);
            *(float4*)(op + l0) = u[m];
        }
    }
}

// ---------------------------------------------------------------------------
// Pass 2 (fp16 path): bits 11..19 (qubits 8..0). Reads __half2 intermediate
// from ws, writes f32 out. Block = 256 threads, tile = 512 h x 32 lows,
// LDS 64 KiB fp16. Row h = 32 complex = 8 slots of 4 complex (16 B);
// slot swizzle j ^ (h&7).
// ---------------------------------------------------------------------------
__global__ __launch_bounds__(256) void rx_pass2_h(
        const float* __restrict__ thetas, const __half2* __restrict__ ws,
        float2* __restrict__ out) {
    __shared__ __half2 buf[16384];                  // 64 KiB
    const int tid = threadIdx.x;
    const int b = blockIdx.x >> 6;
    const int lb = blockIdx.x & 63;                 // 64 low-blocks of 32
    const __half2* pin = ws + ((size_t)b << NQ) + (lb << 5);
    float2* pout = out + ((size_t)b << NQ) + (lb << 5);

    // h-bit i <-> qubit 8-i
    float c[9], sv[9];
#pragma unroll
    for (int i = 0; i < 9; ++i) {
        float th = 0.5f * thetas[b * NQ + (8 - i)];
        c[i]  = bcast_first(cosf(th));
        sv[i] = bcast_first(sinf(th));
    }

    // Stage A: global -> LDS. 16 float4/thread; 8 lanes cover one 128B row chunk.
#pragma unroll
    for (int i = 0; i < 16; ++i) {
        int f = (i << 8) | tid;                     // [0, 4096)
        int h = f >> 3, j = f & 7;
        float4 t = *(const float4*)&pin[h * 2048 + (j << 2)];
        *(float4*)&buf[(h << 5) + ((j ^ (h & 7)) << 2)] = t;
    }
    __syncthreads();

    // Stage B2: h bits 5..8 (qubits 3..0). Thread = (hl = h bits 0..4, slot j).
    {
        const int hl = tid & 31;
        const int j  = tid >> 5;                    // [0,8)
        float4 wa[16], wb[16];
#pragma unroll
        for (int m = 0; m < 16; ++m) {
            int h = (m << 5) | hl;
            float4 V = *(float4*)&buf[(h << 5) + ((j ^ (h & 7)) << 2)];
            float2* half_pair = (float2*)&V;
            wa[m] = h4_to_f4(half_pair[0]);
            wb[m] = h4_to_f4(half_pair[1]);
        }
#pragma unroll
        for (int t = 0; t < 4; ++t) {
            const float C = c[5 + t], SV = sv[5 + t];
            const int msk = 1 << t;
#pragma unroll
            for (int m = 0; m < 16; ++m)
                if (!(m & msk)) {
                    bfly4(C, SV, wa[m], wa[m | msk]);
                    bfly4(C, SV, wb[m], wb[m | msk]);
                }
        }
#pragma unroll
        for (int m = 0; m < 16; ++m) {
            int h = (m << 5) | hl;
            float4 V;
            float2* half_pair = (float2*)&V;
            half_pair[0] = f4_to_h4(wa[m]);
            half_pair[1] = f4_to_h4(wb[m]);
            *(float4*)&buf[(h << 5) + ((j ^ (h & 7)) << 2)] = V;
        }
    }
    __syncthreads();

    // Stage B1: h bits 0..4 (qubits 8..4). Thread = (hh = h bits 5..8, low pair lp).
    // Stores f32 directly to global: per instr, 16 lanes = 256B dense segments.
    {
        const int hh = tid >> 4;                    // [0,16)
        const int lp = tid & 15;                    // low pair: lows {2lp, 2lp+1}
        float4 v[32];
#pragma unroll
        for (int r = 0; r < 32; ++r) {
            int h = (hh << 5) | r;
            float2 d = *(float2*)&buf[(h << 5) + (((lp >> 1) ^ (h & 7)) << 2) + ((lp & 1) << 1)];
            v[r] = h4_to_f4(d);
        }
#pragma unroll
        for (int t = 0; t < 5; ++t) {
            const float C = c[t], SV = sv[t];
            const int msk = 1 << t;
#pragma unroll
            for (int r = 0; r < 32; ++r)
                if (!(r & msk)) bfly4(C, SV, v[r], v[r | msk]);
        }
#pragma unroll
        for (int r = 0; r < 32; ++r) {
            int h = (hh << 5) | r;
            *(float4*)&pout[h * 2048 + (lp << 1)] = v[r];
        }
    }
}

// ---------------------------------------------------------------------------
// Pass 2 (f32 fallback, in-place on out) — R3 version, used only if ws too small
// ---------------------------------------------------------------------------
__device__ __forceinline__ int ppos(int h, int q) {
    return (h << 4) + (((q ^ (h & 7) ^ ((h >> 5) & 7)) & 7) << 1);
}

__global__ __launch_bounds__(256) void rx_pass2_f(
        const float* __restrict__ thetas, float2* __restrict__ out) {
    __shared__ float2 buf[8192];                    // 64 KiB
    const int tid = threadIdx.x;
    const int b = blockIdx.x >> 7;
    const int lb = blockIdx.x & 127;
    float2* p = out + ((size_t)b << NQ) + (lb << 4);

    float c[9], sv[9];
#pragma unroll
    for (int i = 0; i < 9; ++i) {
        float th = 0.5f * thetas[b * NQ + (8 - i)];
        c[i]  = bcast_first(cosf(th));
        sv[i] = bcast_first(sinf(th));
    }

#pragma unroll
    for (int i = 0; i < 16; ++i) {
        int f = (i << 8) | tid;
        int h = f >> 3, j = f & 7;
        float4 t = *(const float4*)(p + h * 2048 + (j << 1));
        *(float4*)&buf[ppos(h, j)] = t;
    }
    __syncthreads();

    {
        const int hl = tid & 31;
        const int j  = tid >> 5;
        float4 w[16];
#pragma unroll
        for (int m = 0; m < 16; ++m)
            w[m] = *(float4*)&buf[ppos((m << 5) | hl, j)];
#pragma unroll
        for (int t = 0; t < 4; ++t) {
            const float C = c[5 + t], SV = sv[5 + t];
            const int msk = 1 << t;
#pragma unroll
            for (int m = 0; m < 16; ++m)
                if (!(m & msk)) bfly4(C, SV, w[m], w[m | msk]);
        }
#pragma unroll
        for (int m = 0; m < 16; ++m)
            *(float4*)&buf[ppos((m << 5) | hl, j)] = w[m];
    }
    __syncthreads();

    {
        const int hh = tid >> 4;
        const int ll = tid & 15;
        float2 v[32];
#pragma unroll
        for (int r = 0; r < 32; ++r) {
            int h = (hh << 5) | r;
            v[r] = buf[ppos(h, ll >> 1) + (ll & 1)];
        }
#pragma unroll
        for (int t = 0; t < 5; ++t) {
            const float C = c[t], SV = sv[t];
            const int msk = 1 << t;
#pragma unroll
            for (int r = 0; r < 32; ++r)
                if (!(r & msk)) bfly(C, SV, v[r], v[r | msk]);
        }
#pragma unroll
        for (int r = 0; r < 32; ++r) {
            int h = (hh << 5) | r;
            p[h * 2048 + ll] = v[r];
        }
    }
}

extern "C" void kernel_launch(void* const* d_in, const int* in_sizes, int n_in,
                              void* d_out, int out_size, void* d_ws, size_t ws_size,
                              hipStream_t stream) {
    const float* phi    = (const float*)d_in[0];
    const float* thetas = (const float*)d_in[1];
    float2* out = (float2*)d_out;
    const size_t need = (size_t)16 * (1u << NQ) * sizeof(__half2);   // 64 MiB
    if (ws_size >= need) {
        __half2* inter = (__half2*)d_ws;
        rx_pass1<true><<<8192, 64, 0, stream>>>(phi, thetas, out, inter);
        rx_pass2_h<<<1024, 256, 0, stream>>>(thetas, inter, out);
    } else {
        rx_pass1<false><<<8192, 64, 0, stream>>>(phi, thetas, out, nullptr);
        rx_pass2_f<<<2048, 256, 0, stream>>>(thetas, out);
    }
}